// Round 2
// baseline (251.969 us; speedup 1.0000x reference)
//
#include <hip/hip_runtime.h>
#include <math.h>

#define N_B 8192
#define N_K 64
#define DD  128

__global__ __launch_bounds__(256) void hybo_kernel(
    const int* __restrict__ u_idx, const int* __restrict__ r_idx,
    const int* __restrict__ v_idx, const float* __restrict__ drug_entity,
    const float* __restrict__ target_entity, const float* __restrict__ relation_bias,
    const float* __restrict__ relation_transform, const float* __restrict__ bias_head,
    const float* __restrict__ bias_tail, float* __restrict__ out)
{
    const int b    = blockIdx.x;
    const int tid  = threadIdx.x;
    const int lane = tid & 63;
    const int wave = tid >> 6;

    __shared__ float x_lds[DD];
    __shared__ float y_lds[DD];
    __shared__ float red_lds[4];

    const int u = u_idx[b];
    const int r = r_idx[b];

    // head fragment: lane l holds head[2l], head[2l+1]
    const float2 h = *reinterpret_cast<const float2*>(drug_entity + (size_t)u * DD + 2 * lane);

    // ---- Phase B: x[e] = dot(W[e,:], head); wave w owns rows [32w, 32w+32) ----
    const float* Wb = relation_transform + (size_t)r * DD * DD;
#pragma unroll 4
    for (int i = 0; i < 32; ++i) {
        const int e = wave * 32 + i;
        const float2 w2 = *reinterpret_cast<const float2*>(Wb + e * DD + 2 * lane);
        float p = fmaf(w2.x, h.x, w2.y * h.y);
        #pragma unroll
        for (int m = 32; m >= 1; m >>= 1) p += __shfl_xor(p, m, 64);
        if (lane == 0) x_lds[e] = p;
    }
    __syncthreads();

    // ---- Phase C: time, renormalization, build y vector ----
    const float x0    = x_lds[0];                       // pre-bias x[0] per reference
    const float timev = 2.5f / (1.0f + expf(-x0)) + 1.1f;

    float xv = 0.0f, sq = 0.0f;
    if (tid < DD) {
        xv = x_lds[tid] + relation_bias[(size_t)r * DD + tid];
        if (tid > 0) sq = xv * xv;                      // nar = x[1:]
    }
    float ps = sq;
    #pragma unroll
    for (int m = 32; m >= 1; m >>= 1) ps += __shfl_xor(ps, m, 64);
    if (lane == 0) red_lds[wave] = ps;
    __syncthreads();
    const float s = red_lds[0] + red_lds[1] + red_lds[2] + red_lds[3];
    const float f = sqrtf((timev * timev - 1.0f) / s);

    // y[0] = -time, y[j] = nar[j-1]*f  ->  cin = sum_j y[j]*tail[j]
    if (tid < DD) y_lds[tid] = (tid == 0) ? -timev : xv * f;
    __syncthreads();

    const float y0 = y_lds[2 * lane];
    const float y1 = y_lds[2 * lane + 1];
    const float bh = bias_head[u];

    // ---- Phase D: 64 tail dots; wave w owns k = w, w+4, ... ----
    for (int kk = wave; kk < N_K; kk += 4) {
        const int v = v_idx[(size_t)b * N_K + kk];
        const float2 t2 = *reinterpret_cast<const float2*>(target_entity + (size_t)v * DD + 2 * lane);
        float p = fmaf(t2.x, y0, t2.y * y1);
        #pragma unroll
        for (int m = 32; m >= 1; m >>= 1) p += __shfl_xor(p, m, 64);
        if (lane == 0)
            out[(size_t)b * N_K + kk] = fmaf(2.0f, p, 8.0f) + bh + bias_tail[v];
    }
}

extern "C" void kernel_launch(void* const* d_in, const int* in_sizes, int n_in,
                              void* d_out, int out_size, void* d_ws, size_t ws_size,
                              hipStream_t stream) {
    const int*   u_idx  = (const int*)d_in[0];
    const int*   r_idx  = (const int*)d_in[1];
    const int*   v_idx  = (const int*)d_in[2];
    const float* drug   = (const float*)d_in[3];
    const float* targ   = (const float*)d_in[4];
    const float* rbias  = (const float*)d_in[5];
    const float* rtrans = (const float*)d_in[6];
    const float* bhead  = (const float*)d_in[7];
    const float* btail  = (const float*)d_in[8];
    float* out = (float*)d_out;

    hipLaunchKernelGGL(hybo_kernel, dim3(N_B), dim3(256), 0, stream,
                       u_idx, r_idx, v_idx, drug, targ, rbias, rtrans, bhead, btail, out);
}

// Round 6
// 195.316 us; speedup vs baseline: 1.2901x; 1.2901x over previous
//
#include <hip/hip_runtime.h>
#include <math.h>

#define N_B 8192
#define N_K 64
#define DD  128

__global__ __launch_bounds__(256) void hybo_kernel(
    const int* __restrict__ u_idx, const int* __restrict__ r_idx,
    const int* __restrict__ v_idx, const float* __restrict__ drug_entity,
    const float* __restrict__ target_entity, const float* __restrict__ relation_bias,
    const float* __restrict__ relation_transform, const float* __restrict__ bias_head,
    const float* __restrict__ bias_tail, float* __restrict__ out)
{
    const int b    = blockIdx.x;
    const int tid  = threadIdx.x;
    const int lane = tid & 63;
    const int wave = tid >> 6;
    const int q    = lane & 15;          // position within 16-lane group
    const int g    = lane >> 4;          // group id within wave (0..3)

    __shared__ float x_lds[DD];          // pre-bias matvec result
    __shared__ float y_lds[DD];          // xv = x + rb (pre-scale)
    __shared__ float red_lds[4];

    const int u = u_idx[b];
    const int r = r_idx[b];

    // ---- early: v indices for phase D (group-uniform broadcast loads) ----
    int vi[4];
#pragma unroll
    for (int i = 0; i < 4; ++i)
        vi[i] = v_idx[(size_t)b * N_K + wave * 16 + i * 4 + g];

    // head slice for this lane's group position: head[8q .. 8q+7]
    const float4 h0 = *reinterpret_cast<const float4*>(drug_entity + (size_t)u * DD + 8 * q);
    const float4 h1 = *reinterpret_cast<const float4*>(drug_entity + (size_t)u * DD + 8 * q + 4);

    // ---- Phase B: x[e] = dot(W[e,:], head) ----
    // wave owns rows [wave*32, wave*32+32); 4 rows per iter (one per 16-lane group)
    const float* Wb = relation_transform + (size_t)r * DD * DD;
    float4 wv[16];
#pragma unroll
    for (int i = 0; i < 8; ++i) {
        const float* row = Wb + (wave * 32 + i * 4 + g) * DD + 8 * q;
        wv[2 * i]     = *reinterpret_cast<const float4*>(row);
        wv[2 * i + 1] = *reinterpret_cast<const float4*>(row + 4);
    }
#pragma unroll
    for (int i = 0; i < 8; ++i) {
        float p;
        p = wv[2 * i].x * h0.x;
        p = fmaf(wv[2 * i].y,     h0.y, p);
        p = fmaf(wv[2 * i].z,     h0.z, p);
        p = fmaf(wv[2 * i].w,     h0.w, p);
        p = fmaf(wv[2 * i + 1].x, h1.x, p);
        p = fmaf(wv[2 * i + 1].y, h1.y, p);
        p = fmaf(wv[2 * i + 1].z, h1.z, p);
        p = fmaf(wv[2 * i + 1].w, h1.w, p);
        p += __shfl_xor(p, 1, 64);
        p += __shfl_xor(p, 2, 64);
        p += __shfl_xor(p, 4, 64);
        p += __shfl_xor(p, 8, 64);
        if (q == 0) x_lds[wave * 32 + i * 4 + g] = p;
    }

    // ---- issue phase-D tail loads now; latency hides under phase C ----
    float4 t0[4], t1[4];
    float  bt[4];
#pragma unroll
    for (int i = 0; i < 4; ++i) {
        const float* trow = target_entity + (size_t)vi[i] * DD + 8 * q;
        t0[i] = *reinterpret_cast<const float4*>(trow);
        t1[i] = *reinterpret_cast<const float4*>(trow + 4);
        bt[i] = bias_tail[vi[i]];
    }

    __syncthreads();

    // ---- Phase C: time, norm factor ----
    const float x0 = x_lds[0];           // pre-bias x[0] per reference
    float xv = 0.0f, sq = 0.0f;
    if (tid < DD) {
        xv = x_lds[tid] + relation_bias[(size_t)r * DD + tid];
        y_lds[tid] = xv;
        if (tid > 0) sq = xv * xv;       // nar = x[1:]
    }
    float ps = sq;
#pragma unroll
    for (int m = 32; m >= 1; m >>= 1) ps += __shfl_xor(ps, m, 64);
    if (lane == 0) red_lds[wave] = ps;
    __syncthreads();

    const float timev = 2.5f / (1.0f + expf(-x0)) + 1.1f;
    const float s = red_lds[0] + red_lds[1] + red_lds[2] + red_lds[3];
    const float f = sqrtf((timev * timev - 1.0f) / s);

    // lane's y slice: y[0] = -time, y[j] = xv[j]*f; cin = dot(y, tail)
    float4 ya = *reinterpret_cast<const float4*>(&y_lds[8 * q]);
    float4 yb = *reinterpret_cast<const float4*>(&y_lds[8 * q + 4]);
    ya.x = (q == 0) ? -timev : ya.x * f;
    ya.y *= f; ya.z *= f; ya.w *= f;
    yb.x *= f; yb.y *= f; yb.z *= f; yb.w *= f;

    const float bh = bias_head[u];

    // ---- Phase D: 16 tails per wave, 4 per iter (one per group) ----
#pragma unroll
    for (int i = 0; i < 4; ++i) {
        float p;
        p = t0[i].x * ya.x;
        p = fmaf(t0[i].y, ya.y, p);
        p = fmaf(t0[i].z, ya.z, p);
        p = fmaf(t0[i].w, ya.w, p);
        p = fmaf(t1[i].x, yb.x, p);
        p = fmaf(t1[i].y, yb.y, p);
        p = fmaf(t1[i].z, yb.z, p);
        p = fmaf(t1[i].w, yb.w, p);
        p += __shfl_xor(p, 1, 64);
        p += __shfl_xor(p, 2, 64);
        p += __shfl_xor(p, 4, 64);
        p += __shfl_xor(p, 8, 64);
        if (q == 0)
            out[(size_t)b * N_K + wave * 16 + i * 4 + g] = fmaf(2.0f, p, 8.0f) + bh + bt[i];
    }
}

extern "C" void kernel_launch(void* const* d_in, const int* in_sizes, int n_in,
                              void* d_out, int out_size, void* d_ws, size_t ws_size,
                              hipStream_t stream) {
    const int*   u_idx  = (const int*)d_in[0];
    const int*   r_idx  = (const int*)d_in[1];
    const int*   v_idx  = (const int*)d_in[2];
    const float* drug   = (const float*)d_in[3];
    const float* targ   = (const float*)d_in[4];
    const float* rbias  = (const float*)d_in[5];
    const float* rtrans = (const float*)d_in[6];
    const float* bhead  = (const float*)d_in[7];
    const float* btail  = (const float*)d_in[8];
    float* out = (float*)d_out;

    hipLaunchKernelGGL(hybo_kernel, dim3(N_B), dim3(256), 0, stream,
                       u_idx, r_idx, v_idx, drug, targ, rbias, rtrans, bhead, btail, out);
}

// Round 7
// 166.216 us; speedup vs baseline: 1.5159x; 1.1751x over previous
//
#include <hip/hip_runtime.h>
#include <math.h>

#define N_B 8192
#define N_K 64
#define DD  128
#define N_RELC 500

// ---------------- Pass 1: group batch indices by relation (counting sort) ----------------
__global__ __launch_bounds__(1024) void sort_kernel(const int* __restrict__ r_idx,
                                                    int* __restrict__ perm,
                                                    int* __restrict__ offs)
{
    __shared__ int hist[512];
    __shared__ int scan[512];
    __shared__ int cur[512];
    const int t = threadIdx.x;
    if (t < 512) hist[t] = 0;
    __syncthreads();

    int rv[8];
#pragma unroll
    for (int k = 0; k < 8; ++k) {
        rv[k] = r_idx[t + 1024 * k];
        atomicAdd(&hist[rv[k]], 1);
    }
    __syncthreads();
    if (t < 512) scan[t] = hist[t];
    __syncthreads();
    // Hillis-Steele inclusive scan over 512 entries
    for (int off = 1; off < 512; off <<= 1) {
        int v = 0;
        if (t < 512 && t >= off) v = scan[t - off];
        __syncthreads();
        if (t < 512) scan[t] += v;
        __syncthreads();
    }
    if (t < 512) {
        const int excl = scan[t] - hist[t];
        cur[t] = excl;
        if (t <= N_RELC) offs[t] = excl;   // offs[500] = 8192
    }
    __syncthreads();
#pragma unroll
    for (int k = 0; k < 8; ++k) {
        const int pos = atomicAdd(&cur[rv[k]], 1);
        perm[pos] = t + 1024 * k;
    }
}

// ---------------- Pass 2: main compute, relation-grouped, XCD-pinned ----------------
// grid = 8 XCDs * 63 relation-classes * 4 slices = 2016.
// bid%8 = XCD (default round-robin assumption); relation r runs only on XCD r%8,
// so W[r] misses L2 once per relation total.
__global__ __launch_bounds__(256) void hybo_main(
    const int* __restrict__ u_idx, const int* __restrict__ v_idx,
    const float* __restrict__ drug_entity, const float* __restrict__ target_entity,
    const float* __restrict__ relation_bias, const float* __restrict__ relation_transform,
    const float* __restrict__ bias_head, const float* __restrict__ bias_tail,
    const int* __restrict__ perm, const int* __restrict__ offs,
    float* __restrict__ out)
{
    const int bid = blockIdx.x;
    const int x   = bid & 7;        // XCD
    const int i   = bid >> 3;       // 0..251
    const int rc  = i >> 2;         // relation class 0..62
    const int s   = i & 3;          // slice 0..3
    const int r   = (rc << 3) | x;
    if (r >= N_RELC) return;

    const int beg = offs[r];
    const int n   = offs[r + 1] - beg;
    if (n <= s) return;             // wg-uniform

    const int tid  = threadIdx.x;
    const int lane = tid & 63;
    const int wave = tid >> 6;
    const int q    = lane & 15;     // position within 16-lane group
    const int g    = lane >> 4;     // group id within wave (0..3)

    __shared__ float x_lds[DD];
    __shared__ float y_lds[DD];
    __shared__ float red_lds[4];

    // relation-uniform data hoisted out of the b-loop
    const float rbv = (tid < DD) ? relation_bias[r * DD + tid] : 0.0f;
    const float* Wb = relation_transform + (size_t)r * (DD * DD);

    for (int p = s; p < n; p += 4) {
        const int b = perm[beg + p];
        const int u = u_idx[b];

        // v indices for phase D
        int vi[4];
#pragma unroll
        for (int ii = 0; ii < 4; ++ii)
            vi[ii] = v_idx[(size_t)b * N_K + wave * 16 + ii * 4 + g];

        const float4 h0 = *reinterpret_cast<const float4*>(drug_entity + (size_t)u * DD + 8 * q);
        const float4 h1 = *reinterpret_cast<const float4*>(drug_entity + (size_t)u * DD + 8 * q + 4);
        const float  bh = bias_head[u];

        // ---- Phase B: x[e] = dot(W[e,:], head); 4 rows/iter (one per 16-lane group) ----
        float4 wv[16];
#pragma unroll
        for (int ii = 0; ii < 8; ++ii) {
            const float* row = Wb + (wave * 32 + ii * 4 + g) * DD + 8 * q;
            wv[2 * ii]     = *reinterpret_cast<const float4*>(row);
            wv[2 * ii + 1] = *reinterpret_cast<const float4*>(row + 4);
        }
#pragma unroll
        for (int ii = 0; ii < 8; ++ii) {
            float p2;
            p2 = wv[2 * ii].x * h0.x;
            p2 = fmaf(wv[2 * ii].y,     h0.y, p2);
            p2 = fmaf(wv[2 * ii].z,     h0.z, p2);
            p2 = fmaf(wv[2 * ii].w,     h0.w, p2);
            p2 = fmaf(wv[2 * ii + 1].x, h1.x, p2);
            p2 = fmaf(wv[2 * ii + 1].y, h1.y, p2);
            p2 = fmaf(wv[2 * ii + 1].z, h1.z, p2);
            p2 = fmaf(wv[2 * ii + 1].w, h1.w, p2);
            p2 += __shfl_xor(p2, 1, 64);
            p2 += __shfl_xor(p2, 2, 64);
            p2 += __shfl_xor(p2, 4, 64);
            p2 += __shfl_xor(p2, 8, 64);
            if (q == 0) x_lds[wave * 32 + ii * 4 + g] = p2;
        }

        // ---- issue phase-D tail loads; latency hides under phase C ----
        float4 t0[4], t1[4];
        float  bt[4];
#pragma unroll
        for (int ii = 0; ii < 4; ++ii) {
            const float* trow = target_entity + (size_t)vi[ii] * DD + 8 * q;
            t0[ii] = *reinterpret_cast<const float4*>(trow);
            t1[ii] = *reinterpret_cast<const float4*>(trow + 4);
            bt[ii] = bias_tail[vi[ii]];
        }

        __syncthreads();

        // ---- Phase C: time, norm factor ----
        const float x0 = x_lds[0];          // pre-bias x[0] per reference
        float xv = 0.0f, sq = 0.0f;
        if (tid < DD) {
            xv = x_lds[tid] + rbv;
            y_lds[tid] = xv;
            if (tid > 0) sq = xv * xv;      // nar = x[1:]
        }
        float ps = sq;
#pragma unroll
        for (int m = 32; m >= 1; m >>= 1) ps += __shfl_xor(ps, m, 64);
        if (lane == 0) red_lds[wave] = ps;
        __syncthreads();

        const float timev = 2.5f / (1.0f + expf(-x0)) + 1.1f;
        const float ssum  = red_lds[0] + red_lds[1] + red_lds[2] + red_lds[3];
        const float f     = sqrtf((timev * timev - 1.0f) / ssum);

        float4 ya = *reinterpret_cast<const float4*>(&y_lds[8 * q]);
        float4 yb = *reinterpret_cast<const float4*>(&y_lds[8 * q + 4]);
        ya.x = (q == 0) ? -timev : ya.x * f;
        ya.y *= f; ya.z *= f; ya.w *= f;
        yb.x *= f; yb.y *= f; yb.z *= f; yb.w *= f;

        // ---- Phase D: 16 tails per wave ----
#pragma unroll
        for (int ii = 0; ii < 4; ++ii) {
            float p2;
            p2 = t0[ii].x * ya.x;
            p2 = fmaf(t0[ii].y, ya.y, p2);
            p2 = fmaf(t0[ii].z, ya.z, p2);
            p2 = fmaf(t0[ii].w, ya.w, p2);
            p2 = fmaf(t1[ii].x, yb.x, p2);
            p2 = fmaf(t1[ii].y, yb.y, p2);
            p2 = fmaf(t1[ii].z, yb.z, p2);
            p2 = fmaf(t1[ii].w, yb.w, p2);
            p2 += __shfl_xor(p2, 1, 64);
            p2 += __shfl_xor(p2, 2, 64);
            p2 += __shfl_xor(p2, 4, 64);
            p2 += __shfl_xor(p2, 8, 64);
            if (q == 0)
                out[(size_t)b * N_K + wave * 16 + ii * 4 + g] = fmaf(2.0f, p2, 8.0f) + bh + bt[ii];
        }
        // no barrier needed here: next iter's x_lds writes race only with
        // pre-barrier-2 reads of THIS iter, which all precede barrier 2.
    }
}

extern "C" void kernel_launch(void* const* d_in, const int* in_sizes, int n_in,
                              void* d_out, int out_size, void* d_ws, size_t ws_size,
                              hipStream_t stream) {
    const int*   u_idx  = (const int*)d_in[0];
    const int*   r_idx  = (const int*)d_in[1];
    const int*   v_idx  = (const int*)d_in[2];
    const float* drug   = (const float*)d_in[3];
    const float* targ   = (const float*)d_in[4];
    const float* rbias  = (const float*)d_in[5];
    const float* rtrans = (const float*)d_in[6];
    const float* bhead  = (const float*)d_in[7];
    const float* btail  = (const float*)d_in[8];
    float* out = (float*)d_out;

    int* perm = (int*)d_ws;            // 8192 ints
    int* offs = perm + N_B;            // 501 ints (512 padded)

    hipLaunchKernelGGL(sort_kernel, dim3(1), dim3(1024), 0, stream, r_idx, perm, offs);
    hipLaunchKernelGGL(hybo_main, dim3(2016), dim3(256), 0, stream,
                       u_idx, v_idx, drug, targ, rbias, rtrans, bhead, btail,
                       perm, offs, out);
}